// Round 13
// baseline (572.124 us; speedup 1.0000x reference)
//
#include <hip/hip_runtime.h>
#include <math.h>

#define N_ATOMS   100000
#define ATOM_FDIM 133
#define HIDDEN    512
#define MAX_NEI   6
#define N_MOLS    4096
#define N_PAIRS   8192

typedef __attribute__((ext_vector_type(8))) short short8;
typedef __attribute__((ext_vector_type(4))) float f32x4;
typedef __attribute__((ext_vector_type(2))) float f32x2;
typedef __attribute__((ext_vector_type(8))) int int8v;

static __device__ __forceinline__ float bf2f(unsigned short h) {
    return __uint_as_float(((unsigned int)h) << 16);
}
static __device__ __forceinline__ unsigned short f2bf(float f) {
    unsigned int u = __float_as_uint(f);
    u += 0x7FFFu + ((u >> 16) & 1u);
    return (unsigned short)(u >> 16);
}
static __device__ __forceinline__ unsigned int pk2bf(float a, float b) {
    unsigned int ua = __float_as_uint(a); ua += 0x7FFFu + ((ua >> 16) & 1u);
    unsigned int ub = __float_as_uint(b); ub += 0x7FFFu + ((ub >> 16) & 1u);
    return (ua >> 16) | (ub & 0xFFFF0000u);
}
// 4x fp32 -> 4x fp8 e4m3 (OCP) packed in a uint
static __device__ __forceinline__ unsigned int pk4f8(float a, float b, float c, float d) {
    unsigned int r = 0;
    r = __builtin_amdgcn_cvt_pk_fp8_f32(a, b, r, false);
    r = __builtin_amdgcn_cvt_pk_fp8_f32(c, d, r, true);
    return r;
}
static __device__ __forceinline__ void gl_lds16(const void* g, void* l) {
    __builtin_amdgcn_global_load_lds(
        (__attribute__((address_space(1))) void*)g,
        (__attribute__((address_space(3))) void*)l, 16, 0, 0);
}

// ---------------------------------------------------------------------------
// f_atoms fp32 [100000,133] -> Xf8 fp8 [100352,256], zero-pad k>=133 and
// rows >= N_ATOMS. One uint4 (16 fp8) per thread.
// ---------------------------------------------------------------------------
__global__ __launch_bounds__(256)
void convert_f8(const float* __restrict__ in, unsigned char* __restrict__ out)
{
    int v = blockIdx.x * 256 + threadIdx.x;
    int row = v >> 4, sl = v & 15;
    int k0 = sl * 16;
    bool rok = row < N_ATOMS;
    const float* r = in + (size_t)row * ATOM_FDIM;
    float f[16];
#pragma unroll
    for (int e = 0; e < 16; ++e) {
        int kk = k0 + e;
        f[e] = (rok && kk < ATOM_FDIM) ? r[kk] : 0.f;
    }
    uint4 u;
    u.x = pk4f8(f[0], f[1], f[2], f[3]);
    u.y = pk4f8(f[4], f[5], f[6], f[7]);
    u.z = pk4f8(f[8], f[9], f[10], f[11]);
    u.w = pk4f8(f[12], f[13], f[14], f[15]);
    *(uint4*)(out + (size_t)row * 256 + k0) = u;
}

// ---------------------------------------------------------------------------
// MX-fp8 (unit scale) MFMA GEMM (atom path), double-buffered stage-ahead:
//   C(fp8[M,N]) = act( [A0_fp8 | A2_fp8] @ Bt^T [+bias] [+addm_fp8] )
// 128x128 tile, BK=128, 4 waves, 4x4 accs of 16x16x128 f8f6f4 (scale=1.0).
// Schedule (bt2-validated): STAGE(t+1) issued before compute(t); one barrier
// per K-slab (the __syncthreads drains the prefetch after compute overlap).
// LDS 64KB: As[2][128][128] + Bs[2][128][128] fp8, XOR 16B-chunk swizzle.
// Epilogue: accs -> bf16 Ct[128][136] (stride-136 pads quads 16 banks apart;
// 272B rows keep 16B alignment) -> fp8 coalesced stores.
// In-place C==addm safe. SWZ: row-block -> XCD (needs gridY%8==0).
// ---------------------------------------------------------------------------
template<bool HAS_A0, bool RELU, bool HAS_BIAS, bool HAS_ADD, bool SWZ>
__global__ __launch_bounds__(256)
void gemm_f8(const unsigned char* __restrict__ A0, int lda0, int K0p,
             const unsigned char* __restrict__ A2, int lda2, int Kp,
             const unsigned char* __restrict__ Bt,
             const float* __restrict__ bias,
             const unsigned char* __restrict__ addm,
             unsigned char* __restrict__ C, int M, int N)
{
    __shared__ unsigned char lds[65536];
    unsigned char* As = lds;                         // [2][128][128] fp8
    unsigned char* Bs = lds + 32768;                 // [2][128][128] fp8
    unsigned short* Ct = (unsigned short*)lds;       // [128][136] bf16 epilogue

    const int tid  = threadIdx.x;
    const int lane = tid & 63;
    const int wid  = tid >> 6;
    int bx, by;
    if (SWZ) {
        int L = blockIdx.y * gridDim.x + blockIdx.x;
        int xcd = L & 7, s = L >> 3;
        bx = s % gridDim.x;
        by = xcd + 8 * (s / gridDim.x);
    } else { bx = blockIdx.x; by = blockIdx.y; }
    const int row0 = by * 128;
    const int col0 = bx * 128;
    const int wm   = wid & 1, wn = wid >> 1;
    const int quad = lane >> 4, l15 = lane & 15;
    const int srow = lane >> 3, schunk = lane & 7;
    const int ssw  = (schunk ^ srow) * 16;           // swizzled global 16B chunk

    f32x4 acc[4][4];
#pragma unroll
    for (int i = 0; i < 4; ++i)
#pragma unroll
        for (int j = 0; j < 4; ++j)
#pragma unroll
            for (int r = 0; r < 4; ++r) acc[i][j][r] = 0.f;

#define STAGE_F8(t, d)                                                        \
    {                                                                         \
        const int k0s = (t) * 128;                                            \
        const unsigned char* Ak;                                              \
        int akof, alda;                                                       \
        if (HAS_A0 && k0s < K0p) { Ak = A0; akof = k0s; alda = lda0; }        \
        else { Ak = A2; akof = HAS_A0 ? (k0s - K0p) : k0s; alda = lda2; }     \
        _Pragma("unroll")                                                     \
        for (int i = 0; i < 4; ++i) {                                         \
            int mbase = wid * 32 + i * 8;                                     \
            int r = row0 + mbase + srow;                                      \
            gl_lds16(Ak + (size_t)r * alda + akof + ssw,                      \
                     As + (d) * 16384 + mbase * 128);                         \
        }                                                                     \
        _Pragma("unroll")                                                     \
        for (int i = 0; i < 4; ++i) {                                         \
            int nbase = wid * 32 + i * 8;                                     \
            int rn = col0 + nbase + srow;                                     \
            gl_lds16(Bt + (size_t)rn * Kp + k0s + ssw,                        \
                     Bs + (d) * 16384 + nbase * 128);                         \
        }                                                                     \
    }

    const int ntiles = Kp >> 7;
    STAGE_F8(0, 0);
    __syncthreads();   // compiler drains vmcnt before barrier: slab 0 ready

    // fragment slots: lane holds k = quad*32 .. +31 (chunks 2q, 2q+1)
    const int s0 = ((2 * quad) ^ (l15 & 7)) * 16;
    const int s1 = ((2 * quad + 1) ^ (l15 & 7)) * 16;

    for (int t = 0; t < ntiles; ++t) {
        const int d = t & 1;
        if (t + 1 < ntiles) STAGE_F8(t + 1, d ^ 1);   // overlaps compute
        const int ab = d * 16384;

        int8v a[4], b[4];
#pragma unroll
        for (int mt = 0; mt < 4; ++mt) {
            int r = wm * 64 + mt * 16 + l15;
            uint4 lo = *(const uint4*)&As[ab + r * 128 + s0];
            uint4 hi = *(const uint4*)&As[ab + r * 128 + s1];
            a[mt][0] = lo.x; a[mt][1] = lo.y; a[mt][2] = lo.z; a[mt][3] = lo.w;
            a[mt][4] = hi.x; a[mt][5] = hi.y; a[mt][6] = hi.z; a[mt][7] = hi.w;
        }
#pragma unroll
        for (int nt = 0; nt < 4; ++nt) {
            int r = wn * 64 + nt * 16 + l15;
            uint4 lo = *(const uint4*)&Bs[ab + r * 128 + s0];
            uint4 hi = *(const uint4*)&Bs[ab + r * 128 + s1];
            b[nt][0] = lo.x; b[nt][1] = lo.y; b[nt][2] = lo.z; b[nt][3] = lo.w;
            b[nt][4] = hi.x; b[nt][5] = hi.y; b[nt][6] = hi.z; b[nt][7] = hi.w;
        }
        __builtin_amdgcn_s_setprio(1);
#pragma unroll
        for (int mt = 0; mt < 4; ++mt)
#pragma unroll
            for (int nt = 0; nt < 4; ++nt)
                acc[mt][nt] = __builtin_amdgcn_mfma_scale_f32_16x16x128_f8f6f4(
                    a[mt], b[nt], acc[mt][nt], 0, 0, 0, 127, 0, 127);
        __builtin_amdgcn_s_setprio(0);
        __syncthreads();   // drains this slab's prefetch; flips buffers
    }
#undef STAGE_F8

    // ---- epilogue: accs -> bf16 Ct[128][136] -> fp8 coalesced stores
#pragma unroll
    for (int mt = 0; mt < 4; ++mt)
#pragma unroll
        for (int nt = 0; nt < 4; ++nt) {
            int cbase = wn * 64 + nt * 16 + l15;
            int rbase = wm * 64 + mt * 16 + quad * 4;
#pragma unroll
            for (int r = 0; r < 4; ++r)
                Ct[(rbase + r) * 136 + cbase] = f2bf(acc[mt][nt][r]);
        }
    __syncthreads();
#pragma unroll
    for (int i = 0; i < 8; ++i) {
        int c = tid + i * 256;                 // 0..2047
        int rr = c >> 4, cc = (c & 15) * 8;
        int m = row0 + rr, n = col0 + cc;
        short8 v = *(const short8*)&Ct[rr * 136 + cc];
        float f[8];
#pragma unroll
        for (int q = 0; q < 8; ++q) f[q] = bf2f((unsigned short)v[q]);
        if (HAS_BIAS) {
            float4 b0 = *(const float4*)(bias + n);
            float4 b1 = *(const float4*)(bias + n + 4);
            f[0] += b0.x; f[1] += b0.y; f[2] += b0.z; f[3] += b0.w;
            f[4] += b1.x; f[5] += b1.y; f[6] += b1.z; f[7] += b1.w;
        }
        if (m < M) {
            if (HAS_ADD) {
                uint2 ad = *(const uint2*)(addm + (size_t)m * N + n);
                f32x2 p;
                p = __builtin_amdgcn_cvt_pk_f32_fp8(ad.x, false); f[0] += p.x; f[1] += p.y;
                p = __builtin_amdgcn_cvt_pk_f32_fp8(ad.x, true);  f[2] += p.x; f[3] += p.y;
                p = __builtin_amdgcn_cvt_pk_f32_fp8(ad.y, false); f[4] += p.x; f[5] += p.y;
                p = __builtin_amdgcn_cvt_pk_f32_fp8(ad.y, true);  f[6] += p.x; f[7] += p.y;
            }
            if (RELU)
#pragma unroll
                for (int q = 0; q < 8; ++q) f[q] = fmaxf(f[q], 0.f);
            uint2 o;
            o.x = pk4f8(f[0], f[1], f[2], f[3]);
            o.y = pk4f8(f[4], f[5], f[6], f[7]);
            *(uint2*)(C + (size_t)m * N + n) = o;
        }
    }
}

// ---------------------------------------------------------------------------
// bf16 MFMA GEMM, 256xBN tile, BK=64, 8 waves (2M x 4N), double-buffered LDS
// with stage(t+1)-before-compute(t) overlap (1 barrier per K-tile).
//   C bf16[M,N] = act(A[M,K] @ Bt[N,K]^T + bias)
// Requires: M % 256 == 0, N % BN == 0, Kp % 64 == 0, grid % 8 == 0.
// Chunked XCD remap: Ls=(L&7)*nwg/8 + L>>3 gives each XCD a contiguous band
// of 4 row-panels (A L2-resident) streaming B once — kills A over-fetch.
// LDS: As[2][256][64] + Bs[2][BN][64] bf16; XOR 16B-chunk swizzle.
// Epilogue: acc -> bf16 Ct[256][BN] in LDS (reuses As/Bs) -> uint4 stores.
// ---------------------------------------------------------------------------
template<int NT, bool RELU, bool HAS_BIAS>
__global__ __launch_bounds__(512, 2)
void gemm_bt2(const unsigned short* __restrict__ A, int lda, int Kp,
              const unsigned short* __restrict__ Bt,
              const float* __restrict__ bias,
              unsigned short* __restrict__ C, int M, int N)
{
    constexpr int BN = NT * 64;
    constexpr int SMEM = 2 * 256 * 64 * 2 + 2 * BN * 64 * 2;  // 128KB / 96KB
    __shared__ unsigned char smem[SMEM];
    unsigned short* As_ = (unsigned short*)smem;                   // [2][256][64]
    unsigned short* Bs_ = (unsigned short*)(smem + 2 * 256 * 64 * 2); // [2][BN][64]
    unsigned short* Ct  = (unsigned short*)smem;                   // [256][BN]

    const int tid  = threadIdx.x;
    const int lane = tid & 63;
    const int wid  = tid >> 6;          // 0..7
    const int wr   = wid >> 2;          // 0..1  M-half
    const int wc   = wid & 3;           // 0..3  N-quarter
    const int quad = lane >> 4, l15 = lane & 15;
    const int srow = lane >> 3, schunk = lane & 7;
    const int ssw  = (schunk ^ srow) * 8;   // pre-swizzled global bf16 chunk

    // chunked XCD remap (bijective; nwg % 8 == 0 for both uses)
    const int L = blockIdx.y * gridDim.x + blockIdx.x;
    const int chunk = (gridDim.x * gridDim.y) >> 3;
    const int Ls = (L & 7) * chunk + (L >> 3);
    const int row0 = (Ls / gridDim.x) * 256;
    const int col0 = (Ls % gridDim.x) * BN;

    f32x4 acc[8][NT];
#pragma unroll
    for (int i = 0; i < 8; ++i)
#pragma unroll
        for (int j = 0; j < NT; ++j)
#pragma unroll
            for (int r = 0; r < 4; ++r) acc[i][j][r] = 0.f;

#define STAGE_TILE(t, d)                                                     \
    {                                                                        \
        const int k0s = (t) * 64;                                            \
        _Pragma("unroll")                                                    \
        for (int i = 0; i < 4; ++i) {                                        \
            int mbase = wid * 32 + i * 8;                                    \
            int r = row0 + mbase + srow;                                     \
            gl_lds16(A + (size_t)r * lda + k0s + ssw,                        \
                     As_ + (d) * (256 * 64) + mbase * 64);                   \
        }                                                                    \
        _Pragma("unroll")                                                    \
        for (int i = 0; i < NT; ++i) {                                       \
            int nbase = wid * (NT * 8) + i * 8;                              \
            int rn = col0 + nbase + srow;                                    \
            gl_lds16(Bt + (size_t)rn * Kp + k0s + ssw,                       \
                     Bs_ + (d) * (BN * 64) + nbase * 64);                    \
        }                                                                    \
    }

    // fragment slot offsets (bf16 units): k-chunk (ks*4+quad) ^ (row&7)
    const int slot0 = ((quad) ^ (l15 & 7)) * 8;
    const int slot1 = ((4 + quad) ^ (l15 & 7)) * 8;

    const int ntiles = Kp >> 6;
    STAGE_TILE(0, 0);
    __syncthreads();   // compiler drains vmcnt before barrier: tile 0 ready

    for (int t = 0; t < ntiles; ++t) {
        const int d = t & 1;
        if (t + 1 < ntiles) STAGE_TILE(t + 1, d ^ 1);   // overlaps compute

        const int abase = d * (256 * 64);
        const int bbase = d * (BN * 64);
        // B fragments (shared across all quadrants of this K-tile)
        short8 bf[NT][2];
#pragma unroll
        for (int nt2 = 0; nt2 < NT; ++nt2) {
            int cn = wc * (NT * 16) + nt2 * 16 + l15;
            bf[nt2][0] = *(const short8*)&Bs_[bbase + cn * 64 + slot0];
            bf[nt2][1] = *(const short8*)&Bs_[bbase + cn * 64 + slot1];
        }
#pragma unroll
        for (int q = 0; q < 4; ++q) {
            short8 af[2][2];
#pragma unroll
            for (int j = 0; j < 2; ++j) {
                int ar = wr * 128 + (q * 2 + j) * 16 + l15;
                af[j][0] = *(const short8*)&As_[abase + ar * 64 + slot0];
                af[j][1] = *(const short8*)&As_[abase + ar * 64 + slot1];
            }
            __builtin_amdgcn_s_setprio(1);
#pragma unroll
            for (int j = 0; j < 2; ++j)
#pragma unroll
                for (int nt2 = 0; nt2 < NT; ++nt2) {
                    acc[q * 2 + j][nt2] = __builtin_amdgcn_mfma_f32_16x16x32_bf16(
                        af[j][0], bf[nt2][0], acc[q * 2 + j][nt2], 0, 0, 0);
                    acc[q * 2 + j][nt2] = __builtin_amdgcn_mfma_f32_16x16x32_bf16(
                        af[j][1], bf[nt2][1], acc[q * 2 + j][nt2], 0, 0, 0);
                }
            __builtin_amdgcn_s_setprio(0);
        }
        __syncthreads();   // drains this wave's stage loads; flips buffers
    }
#undef STAGE_TILE

    // ---- epilogue: acc -> bf16 Ct[256][BN] -> coalesced bf16 stores
#pragma unroll
    for (int mt = 0; mt < 8; ++mt)
#pragma unroll
        for (int nt2 = 0; nt2 < NT; ++nt2) {
            int cbase = wc * (NT * 16) + nt2 * 16 + l15;
            int rbase = wr * 128 + mt * 16 + quad * 4;
#pragma unroll
            for (int r = 0; r < 4; ++r)
                Ct[(rbase + r) * BN + cbase] = f2bf(acc[mt][nt2][r]);
        }
    __syncthreads();
    constexpr int NSTORE = 256 * BN / (512 * 8);    // 16 (BN=256) / 8 (BN=128)
#pragma unroll
    for (int i = 0; i < NSTORE; ++i) {
        int idx = (i * 512 + tid) * 8;
        int rr = idx / BN, cc = idx % BN;
        int m = row0 + rr, n = col0 + cc;
        short8 v = *(const short8*)&Ct[rr * BN + cc];
        float f[8];
#pragma unroll
        for (int q = 0; q < 8; ++q) f[q] = bf2f((unsigned short)v[q]);
        if (HAS_BIAS) {
            float4 b0 = *(const float4*)(bias + n);
            float4 b1 = *(const float4*)(bias + n + 4);
            f[0] += b0.x; f[1] += b0.y; f[2] += b0.z; f[3] += b0.w;
            f[4] += b1.x; f[5] += b1.y; f[6] += b1.z; f[7] += b1.w;
        }
        if (RELU)
#pragma unroll
            for (int q = 0; q < 8; ++q) f[q] = fmaxf(f[q], 0.f);
        uint4 o;
        o.x = pk2bf(f[0], f[1]); o.y = pk2bf(f[2], f[3]);
        o.z = pk2bf(f[4], f[5]); o.w = pk2bf(f[6], f[7]);
        *(uint4*)(C + (size_t)m * N + n) = o;
    }
    (void)M;
}

// ---------------------------------------------------------------------------
// transposes: fp32 -> bf16 / fp8, zero-pad k in [K, Kz), offset koff
// ---------------------------------------------------------------------------
__global__ __launch_bounds__(256)
void transpose_bf16(const float* __restrict__ in, int K, int N,
                    unsigned short* __restrict__ out, int ldOut, int Kz, int koff)
{
    __shared__ float t[32][33];
    const int n0 = blockIdx.x * 32, k0 = blockIdx.y * 32;
    const int tx = threadIdx.x & 31, ty = threadIdx.x >> 5;
#pragma unroll
    for (int i = 0; i < 32; i += 8) {
        int k = k0 + ty + i, n = n0 + tx;
        t[ty + i][tx] = (k < K && n < N) ? in[(size_t)k * N + n] : 0.f;
    }
    __syncthreads();
#pragma unroll
    for (int i = 0; i < 32; i += 8) {
        int n = n0 + ty + i, k = k0 + tx;
        if (n < N && k < Kz)
            out[(size_t)n * ldOut + koff + k] = f2bf(t[tx][ty + i]);
    }
}

__global__ __launch_bounds__(256)
void transpose_f8(const float* __restrict__ in, int K, int N,
                  unsigned char* __restrict__ out, int ldOut, int Kz, int koff)
{
    __shared__ float t[32][33];
    const int n0 = blockIdx.x * 32, k0 = blockIdx.y * 32;
    const int tx = threadIdx.x & 31, ty = threadIdx.x >> 5;
#pragma unroll
    for (int i = 0; i < 32; i += 8) {
        int k = k0 + ty + i, n = n0 + tx;
        t[ty + i][tx] = (k < K && n < N) ? in[(size_t)k * N + n] : 0.f;
    }
    __syncthreads();
#pragma unroll
    for (int i = 0; i < 32; i += 8) {
        int n = n0 + ty + i, k = k0 + tx;
        if (n < N && k < Kz) {
            float v = t[tx][ty + i];
            out[(size_t)n * ldOut + koff + k] =
                (unsigned char)(__builtin_amdgcn_cvt_pk_fp8_f32(v, v, 0, false) & 0xFF);
        }
    }
}

// transpose of (A + B) -> bf16 (FFN fold)
__global__ __launch_bounds__(256)
void transpose_add_bf16(const float* __restrict__ inA, const float* __restrict__ inB,
                        int K, int N, unsigned short* __restrict__ out,
                        int ldOut, int koff)
{
    __shared__ float t[32][33];
    const int n0 = blockIdx.x * 32, k0 = blockIdx.y * 32;
    const int tx = threadIdx.x & 31, ty = threadIdx.x >> 5;
#pragma unroll
    for (int i = 0; i < 32; i += 8) {
        int k = k0 + ty + i, n = n0 + tx;
        float v = 0.f;
        if (k < K && n < N) {
            v = inA[(size_t)k * N + n];
            if (inB) v += inB[(size_t)k * N + n];
        }
        t[ty + i][tx] = v;
    }
    __syncthreads();
#pragma unroll
    for (int i = 0; i < 32; i += 8) {
        int n = n0 + ty + i, k = k0 + tx;
        if (n < N && k < K)
            out[(size_t)n * ldOut + koff + k] = f2bf(t[tx][ty + i]);
    }
}

// ---------------------------------------------------------------------------
// gather-sum over fp8: dst[a,:] = sum_j (RELU? relu:id)(src[nei[a,j],:])
// ---------------------------------------------------------------------------
template<bool RELU>
__global__ __launch_bounds__(256)
void gather_f8(const unsigned char* __restrict__ src,
               const int* __restrict__ nei, unsigned char* __restrict__ dst)
{
    const int atom = blockIdx.x * 8 + (threadIdx.x >> 5);
    const int l32  = threadIdx.x & 31;
    const int off  = l32 * 16;
    const int* np_ = nei + (size_t)atom * MAX_NEI;
    float s[16];
#pragma unroll
    for (int e = 0; e < 16; ++e) s[e] = 0.f;
#pragma unroll
    for (int j = 0; j < MAX_NEI; ++j) {
        uint4 u = *(const uint4*)(src + (size_t)np_[j] * HIDDEN + off);
        unsigned int w[4] = {u.x, u.y, u.z, u.w};
#pragma unroll
        for (int q = 0; q < 4; ++q) {
            f32x2 lo = __builtin_amdgcn_cvt_pk_f32_fp8(w[q], false);
            f32x2 hi = __builtin_amdgcn_cvt_pk_f32_fp8(w[q], true);
            float v0 = lo.x, v1 = lo.y, v2 = hi.x, v3 = hi.y;
            if (RELU) {
                v0 = fmaxf(v0, 0.f); v1 = fmaxf(v1, 0.f);
                v2 = fmaxf(v2, 0.f); v3 = fmaxf(v3, 0.f);
            }
            s[4 * q] += v0; s[4 * q + 1] += v1; s[4 * q + 2] += v2; s[4 * q + 3] += v3;
        }
    }
    uint4 o;
    o.x = pk4f8(s[0], s[1], s[2], s[3]);
    o.y = pk4f8(s[4], s[5], s[6], s[7]);
    o.z = pk4f8(s[8], s[9], s[10], s[11]);
    o.w = pk4f8(s[12], s[13], s[14], s[15]);
    *(uint4*)(dst + (size_t)atom * HIDDEN + off) = o;
}

// ---------------------------------------------------------------------------
// segment-mean over sorted mol_ids (fp8 in, fp32 out). Empty -> 0.
// ---------------------------------------------------------------------------
__global__ __launch_bounds__(256)
void segmean_f8(const unsigned char* __restrict__ H,
                const int* __restrict__ mol_ids, float* __restrict__ molv)
{
    const int m = blockIdx.x;
    const int d = threadIdx.x * 2;
    int lo = 0, hi = N_ATOMS;
    while (lo < hi) { int mid = (lo + hi) >> 1; if (mol_ids[mid] < m) lo = mid + 1; else hi = mid; }
    const int start = lo;
    hi = N_ATOMS;
    while (lo < hi) { int mid = (lo + hi) >> 1; if (mol_ids[mid] < m + 1) lo = mid + 1; else hi = mid; }
    const int end = lo;
    float s0 = 0.f, s1 = 0.f;
    for (int a = start; a < end; ++a) {
        unsigned int raw = *(const unsigned short*)(H + (size_t)a * HIDDEN + d);
        f32x2 f = __builtin_amdgcn_cvt_pk_f32_fp8(raw, false);
        s0 += f.x; s1 += f.y;
    }
    int cnt = end - start;
    float inv = 1.0f / (float)(cnt > 0 ? cnt : 1);
    float2 o; o.x = s0 * inv; o.y = s1 * inv;
    *(float2*)(molv + (size_t)m * HIDDEN + d) = o;
}

// ---------------------------------------------------------------------------
// feature[p,:] = [e1 | e2 | e1*e2]  (fp32 molv -> bf16, K=1536 FFN fold)
// ---------------------------------------------------------------------------
__global__ __launch_bounds__(128)
void feature_kernel(const float* __restrict__ molv, const int* __restrict__ edges,
                    unsigned short* __restrict__ feat)
{
    const int p  = blockIdx.x;
    const int d4 = threadIdx.x * 4;
    const int i  = edges[p];
    const int j  = edges[N_PAIRS + p];
    float4 a = *(const float4*)(molv + (size_t)i * HIDDEN + d4);
    float4 b = *(const float4*)(molv + (size_t)j * HIDDEN + d4);
    unsigned short* o = feat + (size_t)p * 1536;
    uint2 w;
    w.x = pk2bf(a.x, a.y); w.y = pk2bf(a.z, a.w);
    *(uint2*)(o + d4) = w;
    w.x = pk2bf(b.x, b.y); w.y = pk2bf(b.z, b.w);
    *(uint2*)(o + HIDDEN + d4) = w;
    w.x = pk2bf(a.x * b.x, a.y * b.y); w.y = pk2bf(a.z * b.z, a.w * b.w);
    *(uint2*)(o + 2 * HIDDEN + d4) = w;
}

// ---------------------------------------------------------------------------
__global__ __launch_bounds__(256)
void final_kernel(const unsigned short* __restrict__ H, const float* __restrict__ w,
                  const float* __restrict__ b, float* __restrict__ out)
{
    const int p   = blockIdx.x;
    const int tid = threadIdx.x;
    const unsigned short* row = H + (size_t)p * 1024;
    float s = 0.f;
    for (int i = tid; i < 1024; i += 256) s += bf2f(row[i]) * w[i];
#pragma unroll
    for (int off = 32; off > 0; off >>= 1) s += __shfl_down(s, off, 64);
    __shared__ float red[4];
    if ((tid & 63) == 0) red[tid >> 6] = s;
    __syncthreads();
    if (tid == 0) {
        float t = red[0] + red[1] + red[2] + red[3] + b[0];
        out[p] = 1.0f / (1.0f + expf(-t));
    }
}

// ---------------------------------------------------------------------------
// Workspace (peak 197.6 MB < proven-safe 213.2 MB) — Round-1 layout:
//   I     fp8 [100000,512] @ 0            (51.2 MB)
//   Y     fp8 [100000,512] @ 51,200,000   (51.2 MB)
//   Wt_i  fp8 [512,256]    @ 102,400,000
//   Wch   fp8 [512,512]    @ 102,531,072
//   Wco   fp8 [512,768]    @ 102,793,216  ([Wo1 pad256 | Wo2])
//   Mv    f32 [4096,512]   @ 103,186,432
//   Wt_f0 bf16[2048,1536]  @ 111,575,040
//   Wt_f1 bf16[1024,2048]  @ 117,866,496
//   F     bf16[8192,1536]  @ 122,060,800
//   H1    bf16[8192,2048]  @ 147,226,624
//   H2    bf16[8192,1024]  @ 180,781,056  -> end 197,558,272
//   Xf8   fp8 [100352,256] @ 122,060,800  (aliases F; lifetimes disjoint:
//       Xf8 live steps 0..5, F first written step 7 — stream-ordered, safe)
// OOB: padded 784-row grids read A2(Y)/addm rows < 100352 -> garbage inside
// ws, feeds discarded rows (m<M store guard). A0 (Xf8) is fully zero-padded.
// ---------------------------------------------------------------------------
extern "C" void kernel_launch(void* const* d_in, const int* in_sizes, int n_in,
                              void* d_out, int out_size, void* d_ws, size_t ws_size,
                              hipStream_t stream)
{
    const float* f_atoms = (const float*)d_in[0];
    const int*   a_nei   = (const int*)d_in[1];
    const int*   mol_ids = (const int*)d_in[2];
    const int*   edges   = (const int*)d_in[3];
    const float* W_i     = (const float*)d_in[4];
    const float* W_h     = (const float*)d_in[5];
    const float* W_o     = (const float*)d_in[6];
    const float* b_o     = (const float*)d_in[7];
    const float* W_ffn_i = (const float*)d_in[8];
    const float* b_ffn_i = (const float*)d_in[9];
    const float* W_ffn_1 = (const float*)d_in[10];
    const float* b_ffn_1 = (const float*)d_in[11];
    const float* W_ffn_2 = (const float*)d_in[12];
    const float* b_ffn_2 = (const float*)d_in[13];
    float* out = (float*)d_out;

    char* ws = (char*)d_ws;
    unsigned char*  I     = (unsigned char*)ws;
    unsigned char*  Y     = (unsigned char*)(ws + 51200000);
    unsigned char*  Wt_i  = (unsigned char*)(ws + 102400000);
    unsigned char*  Wch   = (unsigned char*)(ws + 102531072);
    unsigned char*  Wco   = (unsigned char*)(ws + 102793216);
    float*          Mv    = (float*)(ws + 103186432);
    unsigned short* Wt_f0 = (unsigned short*)(ws + 111575040);
    unsigned short* Wt_f1 = (unsigned short*)(ws + 117866496);
    unsigned short* F     = (unsigned short*)(ws + 122060800);
    unsigned short* H1    = (unsigned short*)(ws + 147226624);
    unsigned short* H2    = (unsigned short*)(ws + 180781056);
    unsigned char*  Xf8   = (unsigned char*)(ws + 122060800);  // aliases F

    const float* W0 = W_ffn_i;
    const float* W1 = W_ffn_i + (size_t)512 * 2048;
    const float* W2 = W_ffn_i + (size_t)1024 * 2048;
    const float* W3 = W_ffn_i + (size_t)1536 * 2048;

    // --- all weight prep front-loaded ---
    transpose_f8<<<dim3(16, 8),  256, 0, stream>>>(W_i, 133, 512, Wt_i, 256, 256, 0);
    transpose_f8<<<dim3(16, 16), 256, 0, stream>>>(W_h, 512, 512, Wch, 512, 512, 0);
    transpose_f8<<<dim3(16, 8),  256, 0, stream>>>(W_o, 133, 512, Wco, 768, 256, 0);
    transpose_f8<<<dim3(16, 16), 256, 0, stream>>>(W_o + (size_t)133 * 512,
                                                   512, 512, Wco, 768, 512, 256);
    transpose_add_bf16<<<dim3(64, 16), 256, 0, stream>>>(W0, W2, 512, 2048, Wt_f0, 1536, 0);
    transpose_add_bf16<<<dim3(64, 16), 256, 0, stream>>>(W0, W3, 512, 2048, Wt_f0, 1536, 512);
    transpose_add_bf16<<<dim3(64, 16), 256, 0, stream>>>(W1, nullptr, 512, 2048, Wt_f0, 1536, 1024);
    transpose_bf16<<<dim3(32, 64), 256, 0, stream>>>(W_ffn_1, 2048, 1024, Wt_f1, 2048, 2048, 0);

    // 0) Xf8 = fp8(f_atoms), zero-padded to [100352, 256]
    convert_f8<<<100352 * 16 / 256, 256, 0, stream>>>(f_atoms, Xf8);

    // 1) I = f_atoms @ W_i   (pre-relu inp, fp8; K=256 all-A0)
    gemm_f8<true, false, false, false, true><<<dim3(4, 784), 256, 0, stream>>>(
        Xf8, 256, 256, nullptr, 0, 256, Wt_i, nullptr, nullptr, I, N_ATOMS, HIDDEN);
    // 2) Y = gather-sum(relu(I))
    gather_f8<true><<<N_ATOMS / 8, 256, 0, stream>>>(I, a_nei, Y);
    // 3) I = relu(I + Y @ W_h)   (in-place addm; K=512)
    gemm_f8<false, true, false, true, true><<<dim3(4, 784), 256, 0, stream>>>(
        nullptr, 0, 0, Y, 512, 512, Wch, nullptr, I, I, N_ATOMS, HIDDEN);
    // 4) Y = gather-sum(I)
    gather_f8<false><<<N_ATOMS / 8, 256, 0, stream>>>(I, a_nei, Y);
    // 5) I = relu([f_atoms | Y] @ [Wo1 ; Wo2] + b_o)   (K=768)
    gemm_f8<true, true, true, false, true><<<dim3(4, 784), 256, 0, stream>>>(
        Xf8, 256, 256, Y, 512, 768, Wco, b_o, nullptr, I, N_ATOMS, HIDDEN);
    // 6) Mv = segment-mean(I)
    segmean_f8<<<N_MOLS, 256, 0, stream>>>(I, mol_ids, Mv);
    // 7) F = [e1 | e2 | e1*e2]  (bf16)
    feature_kernel<<<N_PAIRS, 128, 0, stream>>>(Mv, edges, F);
    // 8) H1 = relu(F @ Wt_f0^T + b_ffn_i)   (bf16, 256x256 dbuf kernel)
    gemm_bt2<4, true, true><<<dim3(8, 32), 512, 0, stream>>>(
        F, 1536, 1536, Wt_f0, b_ffn_i, H1, N_PAIRS, 2048);
    // 9) H2 = relu(H1 @ Wt_f1^T + b_ffn_1)  (bf16, 256x128 dbuf kernel)
    gemm_bt2<2, true, true><<<dim3(8, 32), 512, 0, stream>>>(
        H1, 2048, 2048, Wt_f1, b_ffn_1, H2, N_PAIRS, 1024);
    // 10) out = sigmoid(H2 @ W_ffn_2 + b_ffn_2)
    final_kernel<<<N_PAIRS, 256, 0, stream>>>(H2, W_ffn_2, b_ffn_2, out);
    (void)in_sizes; (void)n_in; (void)out_size; (void)ws_size;
}

// Round 14
// 534.444 us; speedup vs baseline: 1.0705x; 1.0705x over previous
//
#include <hip/hip_runtime.h>
#include <math.h>

#define N_ATOMS   100000
#define ATOM_FDIM 133
#define HIDDEN    512
#define MAX_NEI   6
#define N_MOLS    4096
#define N_PAIRS   8192

typedef __attribute__((ext_vector_type(8))) short short8;
typedef __attribute__((ext_vector_type(4))) float f32x4;
typedef __attribute__((ext_vector_type(2))) float f32x2;
typedef __attribute__((ext_vector_type(8))) int int8v;

static __device__ __forceinline__ float bf2f(unsigned short h) {
    return __uint_as_float(((unsigned int)h) << 16);
}
static __device__ __forceinline__ unsigned short f2bf(float f) {
    unsigned int u = __float_as_uint(f);
    u += 0x7FFFu + ((u >> 16) & 1u);
    return (unsigned short)(u >> 16);
}
static __device__ __forceinline__ unsigned int pk2bf(float a, float b) {
    unsigned int ua = __float_as_uint(a); ua += 0x7FFFu + ((ua >> 16) & 1u);
    unsigned int ub = __float_as_uint(b); ub += 0x7FFFu + ((ub >> 16) & 1u);
    return (ua >> 16) | (ub & 0xFFFF0000u);
}
// 4x fp32 -> 4x fp8 e4m3 (OCP) packed in a uint
static __device__ __forceinline__ unsigned int pk4f8(float a, float b, float c, float d) {
    unsigned int r = 0;
    r = __builtin_amdgcn_cvt_pk_fp8_f32(a, b, r, false);
    r = __builtin_amdgcn_cvt_pk_fp8_f32(c, d, r, true);
    return r;
}
static __device__ __forceinline__ void gl_lds16(const void* g, void* l) {
    __builtin_amdgcn_global_load_lds(
        (__attribute__((address_space(1))) void*)g,
        (__attribute__((address_space(3))) void*)l, 16, 0, 0);
}

// ---------------------------------------------------------------------------
// f_atoms fp32 [100000,133] -> Xf8 fp8 [100352,256], zero-pad k>=133 and
// rows >= N_ATOMS. One uint4 (16 fp8) per thread.
// ---------------------------------------------------------------------------
__global__ __launch_bounds__(256)
void convert_f8(const float* __restrict__ in, unsigned char* __restrict__ out)
{
    int v = blockIdx.x * 256 + threadIdx.x;
    int row = v >> 4, sl = v & 15;
    int k0 = sl * 16;
    bool rok = row < N_ATOMS;
    const float* r = in + (size_t)row * ATOM_FDIM;
    float f[16];
#pragma unroll
    for (int e = 0; e < 16; ++e) {
        int kk = k0 + e;
        f[e] = (rok && kk < ATOM_FDIM) ? r[kk] : 0.f;
    }
    uint4 u;
    u.x = pk4f8(f[0], f[1], f[2], f[3]);
    u.y = pk4f8(f[4], f[5], f[6], f[7]);
    u.z = pk4f8(f[8], f[9], f[10], f[11]);
    u.w = pk4f8(f[12], f[13], f[14], f[15]);
    *(uint4*)(out + (size_t)row * 256 + k0) = u;
}

// ---------------------------------------------------------------------------
// MX-fp8 (unit scale) MFMA GEMM (atom path) — R4-verified single-buffer
// 2-barrier structure (57.6 us/dispatch; R13's 64KB dbuf regressed to 86 us
// by cutting occupancy — m132 lesson, reverted).
//   C(fp8[M,N]) = act( [A0_fp8 | A2_fp8] @ Bt^T [+bias] [+addm_fp8] )
// 128x128 tile, BK=128, 4 waves, 4x4 accs of 16x16x128 f8f6f4 (scale=1.0).
// LDS 34.8KB: As/Bs fp8 [128][128] (16KB each), XOR 16B-chunk swizzle;
// epilogue reuses as bf16 Ct[128][136] (stride-136 spreads quad rows
// 16 banks apart; 272B rows keep 16B alignment).
// In-place C==addm safe. SWZ: row-block -> XCD (needs gridY%8==0).
// ---------------------------------------------------------------------------
template<bool HAS_A0, bool RELU, bool HAS_BIAS, bool HAS_ADD, bool SWZ>
__global__ __launch_bounds__(256)
void gemm_f8(const unsigned char* __restrict__ A0, int lda0, int K0p,
             const unsigned char* __restrict__ A2, int lda2, int Kp,
             const unsigned char* __restrict__ Bt,
             const float* __restrict__ bias,
             const unsigned char* __restrict__ addm,
             unsigned char* __restrict__ C, int M, int N)
{
    __shared__ unsigned char lds[34816];             // max(32768, 128*136*2)
    unsigned char* As = lds;                         // fp8 [128][128]
    unsigned char* Bs = lds + 16384;                 // fp8 [128][128]
    unsigned short* Ct = (unsigned short*)lds;       // bf16 [128][136] epilogue

    const int tid  = threadIdx.x;
    const int lane = tid & 63;
    const int wid  = tid >> 6;
    int bx, by;
    if (SWZ) {
        int L = blockIdx.y * gridDim.x + blockIdx.x;
        int xcd = L & 7, s = L >> 3;
        bx = s % gridDim.x;
        by = xcd + 8 * (s / gridDim.x);
    } else { bx = blockIdx.x; by = blockIdx.y; }
    const int row0 = by * 128;
    const int col0 = bx * 128;
    const int wm   = wid & 1, wn = wid >> 1;
    const int quad = lane >> 4, l15 = lane & 15;
    const int srow = lane >> 3, schunk = lane & 7;
    const int ssw  = (schunk ^ srow) * 16;           // swizzled global 16B chunk

    f32x4 acc[4][4];
#pragma unroll
    for (int i = 0; i < 4; ++i)
#pragma unroll
        for (int j = 0; j < 4; ++j)
#pragma unroll
            for (int r = 0; r < 4; ++r) acc[i][j][r] = 0.f;

    for (int k0 = 0; k0 < Kp; k0 += 128) {
        __syncthreads();
        // select A source for this K-slab (wave-uniform branch)
        const unsigned char* Ak;
        int akof, alda;
        if (HAS_A0 && k0 < K0p) { Ak = A0; akof = k0; alda = lda0; }
        else { Ak = A2; akof = HAS_A0 ? (k0 - K0p) : k0; alda = lda2; }
#pragma unroll
        for (int i = 0; i < 4; ++i) {
            int mbase = wid * 32 + i * 8;                 // wave-uniform
            int r = row0 + mbase + srow;
            gl_lds16(Ak + (size_t)r * alda + akof + ssw, &As[mbase * 128]);
        }
#pragma unroll
        for (int i = 0; i < 4; ++i) {
            int nbase = wid * 32 + i * 8;                 // wave-uniform
            int rn = col0 + nbase + srow;
            gl_lds16(Bt + (size_t)rn * Kp + k0 + ssw, &Bs[nbase * 128]);
        }
        __syncthreads();
        // fragment loads: lane holds k = quad*32 .. +31 (chunks 2q, 2q+1)
        const int s0 = ((2 * quad) ^ (l15 & 7)) * 16;
        const int s1 = ((2 * quad + 1) ^ (l15 & 7)) * 16;
        int8v a[4], b[4];
#pragma unroll
        for (int mt = 0; mt < 4; ++mt) {
            int r = wm * 64 + mt * 16 + l15;
            uint4 lo = *(const uint4*)&As[r * 128 + s0];
            uint4 hi = *(const uint4*)&As[r * 128 + s1];
            a[mt][0] = lo.x; a[mt][1] = lo.y; a[mt][2] = lo.z; a[mt][3] = lo.w;
            a[mt][4] = hi.x; a[mt][5] = hi.y; a[mt][6] = hi.z; a[mt][7] = hi.w;
        }
#pragma unroll
        for (int nt = 0; nt < 4; ++nt) {
            int r = wn * 64 + nt * 16 + l15;
            uint4 lo = *(const uint4*)&Bs[r * 128 + s0];
            uint4 hi = *(const uint4*)&Bs[r * 128 + s1];
            b[nt][0] = lo.x; b[nt][1] = lo.y; b[nt][2] = lo.z; b[nt][3] = lo.w;
            b[nt][4] = hi.x; b[nt][5] = hi.y; b[nt][6] = hi.z; b[nt][7] = hi.w;
        }
#pragma unroll
        for (int mt = 0; mt < 4; ++mt)
#pragma unroll
            for (int nt = 0; nt < 4; ++nt)
                acc[mt][nt] = __builtin_amdgcn_mfma_scale_f32_16x16x128_f8f6f4(
                    a[mt], b[nt], acc[mt][nt], 0, 0, 0, 127, 0, 127);
    }

    // ---- epilogue: accs -> bf16 Ct[128][136] -> fp8 coalesced stores
    __syncthreads();
#pragma unroll
    for (int mt = 0; mt < 4; ++mt)
#pragma unroll
        for (int nt = 0; nt < 4; ++nt) {
            int cbase = wn * 64 + nt * 16 + l15;
            int rbase = wm * 64 + mt * 16 + quad * 4;
#pragma unroll
            for (int r = 0; r < 4; ++r)
                Ct[(rbase + r) * 136 + cbase] = f2bf(acc[mt][nt][r]);
        }
    __syncthreads();
#pragma unroll
    for (int i = 0; i < 8; ++i) {
        int c = tid + i * 256;                 // 0..2047
        int rr = c >> 4, cc = (c & 15) * 8;
        int m = row0 + rr, n = col0 + cc;
        short8 v = *(const short8*)&Ct[rr * 136 + cc];
        float f[8];
#pragma unroll
        for (int q = 0; q < 8; ++q) f[q] = bf2f((unsigned short)v[q]);
        if (HAS_BIAS) {
            float4 b0 = *(const float4*)(bias + n);
            float4 b1 = *(const float4*)(bias + n + 4);
            f[0] += b0.x; f[1] += b0.y; f[2] += b0.z; f[3] += b0.w;
            f[4] += b1.x; f[5] += b1.y; f[6] += b1.z; f[7] += b1.w;
        }
        if (m < M) {
            if (HAS_ADD) {
                uint2 ad = *(const uint2*)(addm + (size_t)m * N + n);
                f32x2 p;
                p = __builtin_amdgcn_cvt_pk_f32_fp8(ad.x, false); f[0] += p.x; f[1] += p.y;
                p = __builtin_amdgcn_cvt_pk_f32_fp8(ad.x, true);  f[2] += p.x; f[3] += p.y;
                p = __builtin_amdgcn_cvt_pk_f32_fp8(ad.y, false); f[4] += p.x; f[5] += p.y;
                p = __builtin_amdgcn_cvt_pk_f32_fp8(ad.y, true);  f[6] += p.x; f[7] += p.y;
            }
            if (RELU)
#pragma unroll
                for (int q = 0; q < 8; ++q) f[q] = fmaxf(f[q], 0.f);
            uint2 o;
            o.x = pk4f8(f[0], f[1], f[2], f[3]);
            o.y = pk4f8(f[4], f[5], f[6], f[7]);
            *(uint2*)(C + (size_t)m * N + n) = o;
        }
    }
}

// ---------------------------------------------------------------------------
// bf16 MFMA GEMM, 256xBN tile, BK=64, 8 waves (2M x 4N), double-buffered LDS
// with stage(t+1)-before-compute(t) overlap (1 barrier per K-tile).
//   C bf16[M,N] = act(A[M,K] @ Bt[N,K]^T + bias)
// Requires: M % 256 == 0, N % BN == 0, Kp % 64 == 0, grid % 8 == 0.
// Chunked XCD remap: Ls=(L&7)*nwg/8 + L>>3 gives each XCD a contiguous band
// of 4 row-panels (A L2-resident) streaming B once (R13: inferred ~50us win
// across steps 8+9 — both dropped below the 86us top-5 cutoff).
// LDS: As[2][256][64] + Bs[2][BN][64] bf16; XOR 16B-chunk swizzle.
// Epilogue: acc -> bf16 Ct[256][BN] in LDS (reuses As/Bs) -> uint4 stores.
// ---------------------------------------------------------------------------
template<int NT, bool RELU, bool HAS_BIAS>
__global__ __launch_bounds__(512, 2)
void gemm_bt2(const unsigned short* __restrict__ A, int lda, int Kp,
              const unsigned short* __restrict__ Bt,
              const float* __restrict__ bias,
              unsigned short* __restrict__ C, int M, int N)
{
    constexpr int BN = NT * 64;
    constexpr int SMEM = 2 * 256 * 64 * 2 + 2 * BN * 64 * 2;  // 128KB / 96KB
    __shared__ unsigned char smem[SMEM];
    unsigned short* As_ = (unsigned short*)smem;                   // [2][256][64]
    unsigned short* Bs_ = (unsigned short*)(smem + 2 * 256 * 64 * 2); // [2][BN][64]
    unsigned short* Ct  = (unsigned short*)smem;                   // [256][BN]

    const int tid  = threadIdx.x;
    const int lane = tid & 63;
    const int wid  = tid >> 6;          // 0..7
    const int wr   = wid >> 2;          // 0..1  M-half
    const int wc   = wid & 3;           // 0..3  N-quarter
    const int quad = lane >> 4, l15 = lane & 15;
    const int srow = lane >> 3, schunk = lane & 7;
    const int ssw  = (schunk ^ srow) * 8;   // pre-swizzled global bf16 chunk

    // chunked XCD remap (bijective; nwg % 8 == 0 for both uses)
    const int L = blockIdx.y * gridDim.x + blockIdx.x;
    const int chunk = (gridDim.x * gridDim.y) >> 3;
    const int Ls = (L & 7) * chunk + (L >> 3);
    const int row0 = (Ls / gridDim.x) * 256;
    const int col0 = (Ls % gridDim.x) * BN;

    f32x4 acc[8][NT];
#pragma unroll
    for (int i = 0; i < 8; ++i)
#pragma unroll
        for (int j = 0; j < NT; ++j)
#pragma unroll
            for (int r = 0; r < 4; ++r) acc[i][j][r] = 0.f;

#define STAGE_TILE(t, d)                                                     \
    {                                                                        \
        const int k0s = (t) * 64;                                            \
        _Pragma("unroll")                                                    \
        for (int i = 0; i < 4; ++i) {                                        \
            int mbase = wid * 32 + i * 8;                                    \
            int r = row0 + mbase + srow;                                     \
            gl_lds16(A + (size_t)r * lda + k0s + ssw,                        \
                     As_ + (d) * (256 * 64) + mbase * 64);                   \
        }                                                                    \
        _Pragma("unroll")                                                    \
        for (int i = 0; i < NT; ++i) {                                       \
            int nbase = wid * (NT * 8) + i * 8;                              \
            int rn = col0 + nbase + srow;                                    \
            gl_lds16(Bt + (size_t)rn * Kp + k0s + ssw,                       \
                     Bs_ + (d) * (BN * 64) + nbase * 64);                    \
        }                                                                    \
    }

    // fragment slot offsets (bf16 units): k-chunk (ks*4+quad) ^ (row&7)
    const int slot0 = ((quad) ^ (l15 & 7)) * 8;
    const int slot1 = ((4 + quad) ^ (l15 & 7)) * 8;

    const int ntiles = Kp >> 6;
    STAGE_TILE(0, 0);
    __syncthreads();   // compiler drains vmcnt before barrier: tile 0 ready

    for (int t = 0; t < ntiles; ++t) {
        const int d = t & 1;
        if (t + 1 < ntiles) STAGE_TILE(t + 1, d ^ 1);   // overlaps compute

        const int abase = d * (256 * 64);
        const int bbase = d * (BN * 64);
        // B fragments (shared across all quadrants of this K-tile)
        short8 bf[NT][2];
#pragma unroll
        for (int nt2 = 0; nt2 < NT; ++nt2) {
            int cn = wc * (NT * 16) + nt2 * 16 + l15;
            bf[nt2][0] = *(const short8*)&Bs_[bbase + cn * 64 + slot0];
            bf[nt2][1] = *(const short8*)&Bs_[bbase + cn * 64 + slot1];
        }
#pragma unroll
        for (int q = 0; q < 4; ++q) {
            short8 af[2][2];
#pragma unroll
            for (int j = 0; j < 2; ++j) {
                int ar = wr * 128 + (q * 2 + j) * 16 + l15;
                af[j][0] = *(const short8*)&As_[abase + ar * 64 + slot0];
                af[j][1] = *(const short8*)&As_[abase + ar * 64 + slot1];
            }
            __builtin_amdgcn_s_setprio(1);
#pragma unroll
            for (int j = 0; j < 2; ++j)
#pragma unroll
                for (int nt2 = 0; nt2 < NT; ++nt2) {
                    acc[q * 2 + j][nt2] = __builtin_amdgcn_mfma_f32_16x16x32_bf16(
                        af[j][0], bf[nt2][0], acc[q * 2 + j][nt2], 0, 0, 0);
                    acc[q * 2 + j][nt2] = __builtin_amdgcn_mfma_f32_16x16x32_bf16(
                        af[j][1], bf[nt2][1], acc[q * 2 + j][nt2], 0, 0, 0);
                }
            __builtin_amdgcn_s_setprio(0);
        }
        __syncthreads();   // drains this wave's stage loads; flips buffers
    }
#undef STAGE_TILE

    // ---- epilogue: acc -> bf16 Ct[256][BN] -> coalesced bf16 stores
#pragma unroll
    for (int mt = 0; mt < 8; ++mt)
#pragma unroll
        for (int nt2 = 0; nt2 < NT; ++nt2) {
            int cbase = wc * (NT * 16) + nt2 * 16 + l15;
            int rbase = wr * 128 + mt * 16 + quad * 4;
#pragma unroll
            for (int r = 0; r < 4; ++r)
                Ct[(rbase + r) * BN + cbase] = f2bf(acc[mt][nt2][r]);
        }
    __syncthreads();
    constexpr int NSTORE = 256 * BN / (512 * 8);    // 16 (BN=256) / 8 (BN=128)
#pragma unroll
    for (int i = 0; i < NSTORE; ++i) {
        int idx = (i * 512 + tid) * 8;
        int rr = idx / BN, cc = idx % BN;
        int m = row0 + rr, n = col0 + cc;
        short8 v = *(const short8*)&Ct[rr * BN + cc];
        float f[8];
#pragma unroll
        for (int q = 0; q < 8; ++q) f[q] = bf2f((unsigned short)v[q]);
        if (HAS_BIAS) {
            float4 b0 = *(const float4*)(bias + n);
            float4 b1 = *(const float4*)(bias + n + 4);
            f[0] += b0.x; f[1] += b0.y; f[2] += b0.z; f[3] += b0.w;
            f[4] += b1.x; f[5] += b1.y; f[6] += b1.z; f[7] += b1.w;
        }
        if (RELU)
#pragma unroll
            for (int q = 0; q < 8; ++q) f[q] = fmaxf(f[q], 0.f);
        uint4 o;
        o.x = pk2bf(f[0], f[1]); o.y = pk2bf(f[2], f[3]);
        o.z = pk2bf(f[4], f[5]); o.w = pk2bf(f[6], f[7]);
        *(uint4*)(C + (size_t)m * N + n) = o;
    }
    (void)M;
}

// ---------------------------------------------------------------------------
// transposes: fp32 -> bf16 / fp8, zero-pad k in [K, Kz), offset koff
// ---------------------------------------------------------------------------
__global__ __launch_bounds__(256)
void transpose_bf16(const float* __restrict__ in, int K, int N,
                    unsigned short* __restrict__ out, int ldOut, int Kz, int koff)
{
    __shared__ float t[32][33];
    const int n0 = blockIdx.x * 32, k0 = blockIdx.y * 32;
    const int tx = threadIdx.x & 31, ty = threadIdx.x >> 5;
#pragma unroll
    for (int i = 0; i < 32; i += 8) {
        int k = k0 + ty + i, n = n0 + tx;
        t[ty + i][tx] = (k < K && n < N) ? in[(size_t)k * N + n] : 0.f;
    }
    __syncthreads();
#pragma unroll
    for (int i = 0; i < 32; i += 8) {
        int n = n0 + ty + i, k = k0 + tx;
        if (n < N && k < Kz)
            out[(size_t)n * ldOut + koff + k] = f2bf(t[tx][ty + i]);
    }
}

__global__ __launch_bounds__(256)
void transpose_f8(const float* __restrict__ in, int K, int N,
                  unsigned char* __restrict__ out, int ldOut, int Kz, int koff)
{
    __shared__ float t[32][33];
    const int n0 = blockIdx.x * 32, k0 = blockIdx.y * 32;
    const int tx = threadIdx.x & 31, ty = threadIdx.x >> 5;
#pragma unroll
    for (int i = 0; i < 32; i += 8) {
        int k = k0 + ty + i, n = n0 + tx;
        t[ty + i][tx] = (k < K && n < N) ? in[(size_t)k * N + n] : 0.f;
    }
    __syncthreads();
#pragma unroll
    for (int i = 0; i < 32; i += 8) {
        int n = n0 + ty + i, k = k0 + tx;
        if (n < N && k < Kz) {
            float v = t[tx][ty + i];
            out[(size_t)n * ldOut + koff + k] =
                (unsigned char)(__builtin_amdgcn_cvt_pk_fp8_f32(v, v, 0, false) & 0xFF);
        }
    }
}

// transpose of (A + B) -> bf16 (FFN fold)
__global__ __launch_bounds__(256)
void transpose_add_bf16(const float* __restrict__ inA, const float* __restrict__ inB,
                        int K, int N, unsigned short* __restrict__ out,
                        int ldOut, int koff)
{
    __shared__ float t[32][33];
    const int n0 = blockIdx.x * 32, k0 = blockIdx.y * 32;
    const int tx = threadIdx.x & 31, ty = threadIdx.x >> 5;
#pragma unroll
    for (int i = 0; i < 32; i += 8) {
        int k = k0 + ty + i, n = n0 + tx;
        float v = 0.f;
        if (k < K && n < N) {
            v = inA[(size_t)k * N + n];
            if (inB) v += inB[(size_t)k * N + n];
        }
        t[ty + i][tx] = v;
    }
    __syncthreads();
#pragma unroll
    for (int i = 0; i < 32; i += 8) {
        int n = n0 + ty + i, k = k0 + tx;
        if (n < N && k < K)
            out[(size_t)n * ldOut + koff + k] = f2bf(t[tx][ty + i]);
    }
}

// ---------------------------------------------------------------------------
// gather-sum over fp8: dst[a,:] = sum_j (RELU? relu:id)(src[nei[a,j],:])
// ---------------------------------------------------------------------------
template<bool RELU>
__global__ __launch_bounds__(256)
void gather_f8(const unsigned char* __restrict__ src,
               const int* __restrict__ nei, unsigned char* __restrict__ dst)
{
    const int atom = blockIdx.x * 8 + (threadIdx.x >> 5);
    const int l32  = threadIdx.x & 31;
    const int off  = l32 * 16;
    const int* np_ = nei + (size_t)atom * MAX_NEI;
    float s[16];
#pragma unroll
    for (int e = 0; e < 16; ++e) s[e] = 0.f;
#pragma unroll
    for (int j = 0; j < MAX_NEI; ++j) {
        uint4 u = *(const uint4*)(src + (size_t)np_[j] * HIDDEN + off);
        unsigned int w[4] = {u.x, u.y, u.z, u.w};
#pragma unroll
        for (int q = 0; q < 4; ++q) {
            f32x2 lo = __builtin_amdgcn_cvt_pk_f32_fp8(w[q], false);
            f32x2 hi = __builtin_amdgcn_cvt_pk_f32_fp8(w[q], true);
            float v0 = lo.x, v1 = lo.y, v2 = hi.x, v3 = hi.y;
            if (RELU) {
                v0 = fmaxf(v0, 0.f); v1 = fmaxf(v1, 0.f);
                v2 = fmaxf(v2, 0.f); v3 = fmaxf(v3, 0.f);
            }
            s[4 * q] += v0; s[4 * q + 1] += v1; s[4 * q + 2] += v2; s[4 * q + 3] += v3;
        }
    }
    uint4 o;
    o.x = pk4f8(s[0], s[1], s[2], s[3]);
    o.y = pk4f8(s[4], s[5], s[6], s[7]);
    o.z = pk4f8(s[8], s[9], s[10], s[11]);
    o.w = pk4f8(s[12], s[13], s[14], s[15]);
    *(uint4*)(dst + (size_t)atom * HIDDEN + off) = o;
}

// ---------------------------------------------------------------------------
// segment-mean over sorted mol_ids (fp8 in, fp32 out). Empty -> 0.
// ---------------------------------------------------------------------------
__global__ __launch_bounds__(256)
void segmean_f8(const unsigned char* __restrict__ H,
                const int* __restrict__ mol_ids, float* __restrict__ molv)
{
    const int m = blockIdx.x;
    const int d = threadIdx.x * 2;
    int lo = 0, hi = N_ATOMS;
    while (lo < hi) { int mid = (lo + hi) >> 1; if (mol_ids[mid] < m) lo = mid + 1; else hi = mid; }
    const int start = lo;
    hi = N_ATOMS;
    while (lo < hi) { int mid = (lo + hi) >> 1; if (mol_ids[mid] < m + 1) lo = mid + 1; else hi = mid; }
    const int end = lo;
    float s0 = 0.f, s1 = 0.f;
    for (int a = start; a < end; ++a) {
        unsigned int raw = *(const unsigned short*)(H + (size_t)a * HIDDEN + d);
        f32x2 f = __builtin_amdgcn_cvt_pk_f32_fp8(raw, false);
        s0 += f.x; s1 += f.y;
    }
    int cnt = end - start;
    float inv = 1.0f / (float)(cnt > 0 ? cnt : 1);
    float2 o; o.x = s0 * inv; o.y = s1 * inv;
    *(float2*)(molv + (size_t)m * HIDDEN + d) = o;
}

// ---------------------------------------------------------------------------
// feature[p,:] = [e1 | e2 | e1*e2]  (fp32 molv -> bf16, K=1536 FFN fold)
// ---------------------------------------------------------------------------
__global__ __launch_bounds__(128)
void feature_kernel(const float* __restrict__ molv, const int* __restrict__ edges,
                    unsigned short* __restrict__ feat)
{
    const int p  = blockIdx.x;
    const int d4 = threadIdx.x * 4;
    const int i  = edges[p];
    const int j  = edges[N_PAIRS + p];
    float4 a = *(const float4*)(molv + (size_t)i * HIDDEN + d4);
    float4 b = *(const float4*)(molv + (size_t)j * HIDDEN + d4);
    unsigned short* o = feat + (size_t)p * 1536;
    uint2 w;
    w.x = pk2bf(a.x, a.y); w.y = pk2bf(a.z, a.w);
    *(uint2*)(o + d4) = w;
    w.x = pk2bf(b.x, b.y); w.y = pk2bf(b.z, b.w);
    *(uint2*)(o + HIDDEN + d4) = w;
    w.x = pk2bf(a.x * b.x, a.y * b.y); w.y = pk2bf(a.z * b.z, a.w * b.w);
    *(uint2*)(o + 2 * HIDDEN + d4) = w;
}

// ---------------------------------------------------------------------------
__global__ __launch_bounds__(256)
void final_kernel(const unsigned short* __restrict__ H, const float* __restrict__ w,
                  const float* __restrict__ b, float* __restrict__ out)
{
    const int p   = blockIdx.x;
    const int tid = threadIdx.x;
    const unsigned short* row = H + (size_t)p * 1024;
    float s = 0.f;
    for (int i = tid; i < 1024; i += 256) s += bf2f(row[i]) * w[i];
#pragma unroll
    for (int off = 32; off > 0; off >>= 1) s += __shfl_down(s, off, 64);
    __shared__ float red[4];
    if ((tid & 63) == 0) red[tid >> 6] = s;
    __syncthreads();
    if (tid == 0) {
        float t = red[0] + red[1] + red[2] + red[3] + b[0];
        out[p] = 1.0f / (1.0f + expf(-t));
    }
}

// ---------------------------------------------------------------------------
// Workspace (peak 197.6 MB < proven-safe 213.2 MB) — Round-1 layout:
//   I     fp8 [100000,512] @ 0            (51.2 MB)
//   Y     fp8 [100000,512] @ 51,200,000   (51.2 MB)
//   Wt_i  fp8 [512,256]    @ 102,400,000
//   Wch   fp8 [512,512]    @ 102,531,072
//   Wco   fp8 [512,768]    @ 102,793,216  ([Wo1 pad256 | Wo2])
//   Mv    f32 [4096,512]   @ 103,186,432
//   Wt_f0 bf16[2048,1536]  @ 111,575,040
//   Wt_f1 bf16[1024,2048]  @ 117,866,496
//   F     bf16[8192,1536]  @ 122,060,800
//   H1    bf16[8192,2048]  @ 147,226,624
//   H2    bf16[8192,1024]  @ 180,781,056  -> end 197,558,272
//   Xf8   fp8 [100352,256] @ 122,060,800  (aliases F; lifetimes disjoint:
//       Xf8 live steps 0..5, F first written step 7 — stream-ordered, safe)
// OOB: padded 784-row grids read A2(Y)/addm rows < 100352 -> garbage inside
// ws, feeds discarded rows (m<M store guard). A0 (Xf8) is fully zero-padded.
// ---------------------------------------------------------------------------
extern "C" void kernel_launch(void* const* d_in, const int* in_sizes, int n_in,
                              void* d_out, int out_size, void* d_ws, size_t ws_size,
                              hipStream_t stream)
{
    const float* f_atoms = (const float*)d_in[0];
    const int*   a_nei   = (const int*)d_in[1];
    const int*   mol_ids = (const int*)d_in[2];
    const int*   edges   = (const int*)d_in[3];
    const float* W_i     = (const float*)d_in[4];
    const float* W_h     = (const float*)d_in[5];
    const float* W_o     = (const float*)d_in[6];
    const float* b_o     = (const float*)d_in[7];
    const float* W_ffn_i = (const float*)d_in[8];
    const float* b_ffn_i = (const float*)d_in[9];
    const float* W_ffn_1 = (const float*)d_in[10];
    const float* b_ffn_1 = (const float*)d_in[11];
    const float* W_ffn_2 = (const float*)d_in[12];
    const float* b_ffn_2 = (const float*)d_in[13];
    float* out = (float*)d_out;

    char* ws = (char*)d_ws;
    unsigned char*  I     = (unsigned char*)ws;
    unsigned char*  Y     = (unsigned char*)(ws + 51200000);
    unsigned char*  Wt_i  = (unsigned char*)(ws + 102400000);
    unsigned char*  Wch   = (unsigned char*)(ws + 102531072);
    unsigned char*  Wco   = (unsigned char*)(ws + 102793216);
    float*          Mv    = (float*)(ws + 103186432);
    unsigned short* Wt_f0 = (unsigned short*)(ws + 111575040);
    unsigned short* Wt_f1 = (unsigned short*)(ws + 117866496);
    unsigned short* F     = (unsigned short*)(ws + 122060800);
    unsigned short* H1    = (unsigned short*)(ws + 147226624);
    unsigned short* H2    = (unsigned short*)(ws + 180781056);
    unsigned char*  Xf8   = (unsigned char*)(ws + 122060800);  // aliases F

    const float* W0 = W_ffn_i;
    const float* W1 = W_ffn_i + (size_t)512 * 2048;
    const float* W2 = W_ffn_i + (size_t)1024 * 2048;
    const float* W3 = W_ffn_i + (size_t)1536 * 2048;

    // --- all weight prep front-loaded ---
    transpose_f8<<<dim3(16, 8),  256, 0, stream>>>(W_i, 133, 512, Wt_i, 256, 256, 0);
    transpose_f8<<<dim3(16, 16), 256, 0, stream>>>(W_h, 512, 512, Wch, 512, 512, 0);
    transpose_f8<<<dim3(16, 8),  256, 0, stream>>>(W_o, 133, 512, Wco, 768, 256, 0);
    transpose_f8<<<dim3(16, 16), 256, 0, stream>>>(W_o + (size_t)133 * 512,
                                                   512, 512, Wco, 768, 512, 256);
    transpose_add_bf16<<<dim3(64, 16), 256, 0, stream>>>(W0, W2, 512, 2048, Wt_f0, 1536, 0);
    transpose_add_bf16<<<dim3(64, 16), 256, 0, stream>>>(W0, W3, 512, 2048, Wt_f0, 1536, 512);
    transpose_add_bf16<<<dim3(64, 16), 256, 0, stream>>>(W1, nullptr, 512, 2048, Wt_f0, 1536, 1024);
    transpose_bf16<<<dim3(32, 64), 256, 0, stream>>>(W_ffn_1, 2048, 1024, Wt_f1, 2048, 2048, 0);

    // 0) Xf8 = fp8(f_atoms), zero-padded to [100352, 256]
    convert_f8<<<100352 * 16 / 256, 256, 0, stream>>>(f_atoms, Xf8);

    // 1) I = f_atoms @ W_i   (pre-relu inp, fp8; K=256 all-A0)
    gemm_f8<true, false, false, false, true><<<dim3(4, 784), 256, 0, stream>>>(
        Xf8, 256, 256, nullptr, 0, 256, Wt_i, nullptr, nullptr, I, N_ATOMS, HIDDEN);
    // 2) Y = gather-sum(relu(I))
    gather_f8<true><<<N_ATOMS / 8, 256, 0, stream>>>(I, a_nei, Y);
    // 3) I = relu(I + Y @ W_h)   (in-place addm; K=512)
    gemm_f8<false, true, false, true, true><<<dim3(4, 784), 256, 0, stream>>>(
        nullptr, 0, 0, Y, 512, 512, Wch, nullptr, I, I, N_ATOMS, HIDDEN);
    // 4) Y = gather-sum(I)
    gather_f8<false><<<N_ATOMS / 8, 256, 0, stream>>>(I, a_nei, Y);
    // 5) I = relu([f_atoms | Y] @ [Wo1 ; Wo2] + b_o)   (K=768)
    gemm_f8<true, true, true, false, true><<<dim3(4, 784), 256, 0, stream>>>(
        Xf8, 256, 256, Y, 512, 768, Wco, b_o, nullptr, I, N_ATOMS, HIDDEN);
    // 6) Mv = segment-mean(I)
    segmean_f8<<<N_MOLS, 256, 0, stream>>>(I, mol_ids, Mv);
    // 7) F = [e1 | e2 | e1*e2]  (bf16)
    feature_kernel<<<N_PAIRS, 128, 0, stream>>>(Mv, edges, F);
    // 8) H1 = relu(F @ Wt_f0^T + b_ffn_i)   (bf16, 256x256 dbuf kernel)
    gemm_bt2<4, true, true><<<dim3(8, 32), 512, 0, stream>>>(
        F, 1536, 1536, Wt_f0, b_ffn_i, H1, N_PAIRS, 2048);
    // 9) H2 = relu(H1 @ Wt_f1^T + b_ffn_1)  (bf16, 256x128 dbuf kernel)
    gemm_bt2<2, true, true><<<dim3(8, 32), 512, 0, stream>>>(
        H1, 2048, 2048, Wt_f1, b_ffn_1, H2, N_PAIRS, 1024);
    // 10) out = sigmoid(H2 @ W_ffn_2 + b_ffn_2)
    final_kernel<<<N_PAIRS, 256, 0, stream>>>(H2, W_ffn_2, b_ffn_2, out);
    (void)in_sizes; (void)n_in; (void)out_size; (void)ws_size;
}